// Round 4
// baseline (160.623 us; speedup 1.0000x reference)
//
#include <hip/hip_runtime.h>
#include <cstddef>

#define K 64
#define D 768
#define D4 192   // D/4

__device__ __forceinline__ float d4f(float4 a, float4 b) {
  return a.x*b.x + a.y*b.y + a.z*b.z + a.w*b.w;
}
__device__ __forceinline__ float4 a4(float4 a, float4 b) {
  return make_float4(a.x+b.x, a.y+b.y, a.z+b.z, a.w+b.w);
}
__device__ __forceinline__ unsigned short f2bf(float x) {
  unsigned int u = __float_as_uint(x);
  unsigned int r = (u + 0x7FFFu + ((u >> 16) & 1u)) >> 16;
  return (unsigned short)r;
}

typedef __attribute__((ext_vector_type(8)))  short bf16x8;
typedef __attribute__((ext_vector_type(16))) float f32x16;

// =====================================================================
// FAST PATH (N=32768, NC=256, C=128)
// =====================================================================
#define NCF 256
#define CF  128

// ---- K1c: cast cavg to bf16 + exact ||row||^2 ----
__global__ __launch_bounds__(256) void k1c(
    const float* __restrict__ cavg, unsigned short* __restrict__ cavgb,
    float* __restrict__ cn2)
{
  int wave = blockIdx.x * 4 + (threadIdx.x >> 6);
  int l = threadIdx.x & 63;
  if (wave >= K) return;
  const float* src = cavg + (size_t)wave * D;
  unsigned short* dst = cavgb + (size_t)wave * D;
  float sq = 0.f;
#pragma unroll
  for (int t = 0; t < 3; ++t) {
    float4 v = ((const float4*)src)[t * 64 + l];
    sq += v.x*v.x + v.y*v.y + v.z*v.z + v.w*v.w;
    ushort4 o; o.x = f2bf(v.x); o.y = f2bf(v.y); o.z = f2bf(v.z); o.w = f2bf(v.w);
    ((ushort4*)dst)[t * 64 + l] = o;
  }
#pragma unroll
  for (int m = 1; m <= 32; m <<= 1) sq += __shfl_xor(sq, m);
  if (l == 0) cn2[wave] = sq;
}

// ---- K2f: fused cast + per-chunk sums GEMM ----
// Reads f32 inputs once; emits Vb (bf16), pv (exact f32), sums (f32), cnts.
#define LDT 260   // V-tile row stride (bf16), conflict-free u16 column reads
#define LDM 136   // Mt row stride
__global__ __launch_bounds__(256) void k2_fused(
    const float* __restrict__ inputs, const int* __restrict__ labels,
    unsigned short* __restrict__ Vb, float* __restrict__ pv,
    float* __restrict__ sums, int* __restrict__ cnts_t)
{
  __shared__ unsigned short Vt[128 * LDT];   // 66560 B
  __shared__ unsigned short Mt[64 * LDM];    // 17408 B
  __shared__ float pvrow[128];
  const int m = blockIdx.x;
  const int tid = threadIdx.x;
  const int w = tid >> 6, l = tid & 63;
  const int r31 = l & 31, kh = l >> 5;

  for (int e = tid; e < 64 * LDM / 2; e += 256) ((unsigned int*)Mt)[e] = 0u;
  if (tid < 128) pvrow[tid] = 0.f;
  __syncthreads();
  if (tid < 128) {
    int lab = labels[m * 128 + tid];
    Mt[lab * LDM + tid] = 0x3F80;   // 1.0 bf16
  }
  __syncthreads();
  if (tid < 64) {
    int c = 0;
    for (int j = 0; j < 128; ++j) c += (Mt[tid * LDM + j] != 0);
    cnts_t[tid * NCF + m] = c;
  }

  f32x16 acc[2][2];
  for (int kd = 0; kd < 3; ++kd) {
#pragma unroll
    for (int ct = 0; ct < 2; ++ct)
#pragma unroll
      for (int ti = 0; ti < 2; ++ti) acc[ct][ti] = (f32x16){};
    __syncthreads();
    // stage: f32 -> bf16 into Vt (LDS) + Vb (global) + pv partials
#pragma unroll 4
    for (int it = 0; it < 16; ++it) {
      int flat = it * 256 + tid;
      int row = flat >> 5, c16 = flat & 31;
      const float* src = inputs + (size_t)(m * 128 + row) * D + kd * 256 + c16 * 8;
      float4 f0 = *(const float4*)src;
      float4 f1 = *(const float4*)(src + 4);
      float sq = d4f(f0, f0) + d4f(f1, f1);
#pragma unroll
      for (int s = 1; s <= 16; s <<= 1) sq += __shfl_xor(sq, s);
      if (c16 == 0) pvrow[row] += sq;      // unique thread per row across all kd
      ushort4 o0, o1;
      o0.x = f2bf(f0.x); o0.y = f2bf(f0.y); o0.z = f2bf(f0.z); o0.w = f2bf(f0.w);
      o1.x = f2bf(f1.x); o1.y = f2bf(f1.y); o1.z = f2bf(f1.z); o1.w = f2bf(f1.w);
      *(ushort4*)(Vt + row * LDT + c16 * 8)     = o0;
      *(ushort4*)(Vt + row * LDT + c16 * 8 + 4) = o1;
      uint4 u;
      u.x = (unsigned)o0.x | ((unsigned)o0.y << 16);
      u.y = (unsigned)o0.z | ((unsigned)o0.w << 16);
      u.z = (unsigned)o1.x | ((unsigned)o1.y << 16);
      u.w = (unsigned)o1.z | ((unsigned)o1.w << 16);
      *(uint4*)(Vb + (size_t)(m * 128 + row) * D + kd * 256 + c16 * 8) = u;
    }
    __syncthreads();
#pragma unroll
    for (int kk = 0; kk < 8; ++kk) {
      bf16x8 a0 = *(const bf16x8*)(Mt + (r31) * LDM + kk * 16 + kh * 8);
      bf16x8 a1 = *(const bf16x8*)(Mt + (32 + r31) * LDM + kk * 16 + kh * 8);
#pragma unroll
      for (int ti = 0; ti < 2; ++ti) {
        int td = w + ti * 4;
        bf16x8 b;
#pragma unroll
        for (int r = 0; r < 8; ++r)
          b[r] = *(const short*)(Vt + (kk * 16 + kh * 8 + r) * LDT + td * 32 + r31);
        acc[0][ti] = __builtin_amdgcn_mfma_f32_32x32x16_bf16(a0, b, acc[0][ti], 0, 0, 0);
        acc[1][ti] = __builtin_amdgcn_mfma_f32_32x32x16_bf16(a1, b, acc[1][ti], 0, 0, 0);
      }
    }
    float* sp = sums + (size_t)m * (K * D) + kd * 256;
#pragma unroll
    for (int ct = 0; ct < 2; ++ct)
#pragma unroll
      for (int ti = 0; ti < 2; ++ti) {
        int td = w + ti * 4;
#pragma unroll
        for (int q = 0; q < 16; ++q) {
          int kcls = ct * 32 + (q & 3) + 8 * (q >> 2) + 4 * kh;
          sp[(size_t)kcls * D + td * 32 + r31] = acc[ct][ti][q];
        }
      }
  }
  __syncthreads();
  if (tid < 128) pv[m * 128 + tid] = pvrow[tid];
}

// ---- K2b: exclusive scan of transposed counts ----
__global__ void k2b_scan_cnts(int* __restrict__ cnts_t, int NC)
{
  int k = threadIdx.x;
  int run = 0;
  int* p = cnts_t + k * NC;
  for (int m = 0; m < NC; ++m) { int t = p[m]; p[m] = run; run += t; }
}

// ---- K3a: level-1 exclusive scan (16 chunks/group, in place) + group totals ----
__global__ __launch_bounds__(256) void k3a_scan_lo(float* __restrict__ sums, float* __restrict__ aux)
{
  int g   = blockIdx.x / 192;
  int col = (blockIdx.x % 192) * 256 + threadIdx.x;
  float run = 0.f;
  for (int m = g * 16; m < g * 16 + 16; ++m) {
    size_t idx = (size_t)m * (K * D) + col;
    float t = sums[idx]; sums[idx] = run; run += t;
  }
  aux[(size_t)g * (K * D) + col] = run;
}

// ---- K3b: scan group totals ----
__global__ __launch_bounds__(256) void k3b_scan_hi(float* __restrict__ aux)
{
  int col = blockIdx.x * 256 + threadIdx.x;
  float run = 0.f;
  for (int g = 0; g < 16; ++g) {
    size_t idx = (size_t)g * (K * D) + col;
    float t = aux[idx]; aux[idx] = run; run += t;
  }
}

// ---- K4: fused GEMMs + in-LDS norm-recurrence epilogue ----
// B-tile rows 0-63 sourced from scanned f32 sums+aux (convert in-flight, bn2 in LDS);
// rows 64-127 from cavgb. Epilogue: wave 0, lanes = classes.
#define LDV 264
#define LDS2 136
#define LDD 132   // f32 dot LDS stride
__global__ __launch_bounds__(256) void k4_mega(
    const unsigned short* __restrict__ Vb, const float* __restrict__ sums,
    const float* __restrict__ aux, const unsigned short* __restrict__ cavgb,
    const int* __restrict__ labels, const float* __restrict__ pv,
    const int* __restrict__ cnts_t, const float* __restrict__ cn2,
    float* __restrict__ out)
{
  __shared__ unsigned short bufV[128 * LDV];   // V tile; later f32 dot[128][132]
  __shared__ unsigned short bufB[128 * LDV];   // B tile; later ldsS + Mt
  __shared__ float bn2L[64];
  __shared__ float pvL[128];
  __shared__ int   labL[128];
  const int m = blockIdx.x;
  const int g = m >> 4;
  const int tid = threadIdx.x, w = tid >> 6, l = tid & 63;
  const int r31 = l & 31, kh = l >> 5;

  if (tid < 64) bn2L[tid] = 0.f;
  if (tid < 128) { pvL[tid] = pv[m * 128 + tid]; labL[tid] = labels[m * 128 + tid]; }
  __syncthreads();

  f32x16 accP[4], accS[4];
#pragma unroll
  for (int t = 0; t < 4; ++t) { accP[t] = (f32x16){}; accS[t] = (f32x16){}; }

  for (int kd = 0; kd < 3; ++kd) {
#pragma unroll 4
    for (int it = 0; it < 16; ++it) {
      int flat = it * 256 + tid;
      int row = flat >> 5, c16 = flat & 31;
      *(uint4*)(bufV + row * LDV + c16 * 8) =
          *(const uint4*)(Vb + (size_t)(m * 128 + row) * D + kd * 256 + c16 * 8);
      if (row < 64) {
        const float* sp = sums + ((size_t)m * K + row) * D + kd * 256 + c16 * 8;
        const float* ap = aux + ((size_t)g * K + row) * D + kd * 256 + c16 * 8;
        float4 s0 = *(const float4*)sp,       s1 = *(const float4*)(sp + 4);
        float4 a0 = *(const float4*)ap,       a1 = *(const float4*)(ap + 4);
        float4 b0 = a4(s0, a0), b1 = a4(s1, a1);
        float sq = d4f(b0, b0) + d4f(b1, b1);
#pragma unroll
        for (int s = 1; s <= 16; s <<= 1) sq += __shfl_xor(sq, s);
        if (c16 == 0) bn2L[row] += sq;    // unique thread per row across all kd
        ushort4 o0, o1;
        o0.x = f2bf(b0.x); o0.y = f2bf(b0.y); o0.z = f2bf(b0.z); o0.w = f2bf(b0.w);
        o1.x = f2bf(b1.x); o1.y = f2bf(b1.y); o1.z = f2bf(b1.z); o1.w = f2bf(b1.w);
        *(ushort4*)(bufB + row * LDV + c16 * 8)     = o0;
        *(ushort4*)(bufB + row * LDV + c16 * 8 + 4) = o1;
      } else {
        *(uint4*)(bufB + row * LDV + c16 * 8) =
            *(const uint4*)(cavgb + (size_t)(row - 64) * D + kd * 256 + c16 * 8);
      }
    }
    __syncthreads();
#pragma unroll 4
    for (int kk = 0; kk < 16; ++kk) {
      bf16x8 av = *(const bf16x8*)(bufV + (32 * w + r31) * LDV + kk * 16 + kh * 8);
#pragma unroll
      for (int t = 0; t < 4; ++t) {
        bf16x8 bB = *(const bf16x8*)(bufB + (32 * t + r31) * LDV + kk * 16 + kh * 8);
        accP[t] = __builtin_amdgcn_mfma_f32_32x32x16_bf16(av, bB, accP[t], 0, 0, 0);
        bf16x8 bV = *(const bf16x8*)(bufV + (32 * t + r31) * LDV + kk * 16 + kh * 8);
        accS[t] = __builtin_amdgcn_mfma_f32_32x32x16_bf16(av, bV, accS[t], 0, 0, 0);
      }
    }
    __syncthreads();
  }

  // masked S -> bf16 (strict lower) + one-hot Mt, then corr GEMM
  unsigned short* ldsS = bufB;
  unsigned short* Mt   = bufB + 128 * LDS2;
#pragma unroll
  for (int t = 0; t < 4; ++t)
#pragma unroll
    for (int q = 0; q < 16; ++q) {
      int i = 32 * w + (q & 3) + 8 * (q >> 2) + 4 * kh;
      int j = 32 * t + r31;
      ldsS[i * LDS2 + j] = (j < i) ? f2bf(accS[t][q]) : (unsigned short)0;
    }
  {
    int j = tid & 127;
    int lab = labL[j];
    int kbase = (tid >> 7) * 32;
#pragma unroll 8
    for (int kk = 0; kk < 32; ++kk) {
      int k = kbase + kk;
      Mt[k * LDS2 + j] = (lab == k) ? (unsigned short)0x3F80 : (unsigned short)0;
    }
  }
  __syncthreads();

#pragma unroll 2
  for (int kk = 0; kk < 8; ++kk) {
    bf16x8 aS = *(const bf16x8*)(ldsS + (32 * w + r31) * LDS2 + kk * 16 + kh * 8);
    bf16x8 b0 = *(const bf16x8*)(Mt + (r31) * LDS2 + kk * 16 + kh * 8);
    bf16x8 b1 = *(const bf16x8*)(Mt + (32 + r31) * LDS2 + kk * 16 + kh * 8);
    accP[0] = __builtin_amdgcn_mfma_f32_32x32x16_bf16(aS, b0, accP[0], 0, 0, 0);
    accP[1] = __builtin_amdgcn_mfma_f32_32x32x16_bf16(aS, b1, accP[1], 0, 0, 0);
  }

  // dot matrix -> LDS (reuse bufV), then wave-0 epilogue
  float* dotL = (float*)bufV;
  __syncthreads();
#pragma unroll
  for (int t = 0; t < 4; ++t)
#pragma unroll
    for (int q = 0; q < 16; ++q) {
      int i = 32 * w + (q & 3) + 8 * (q >> 2) + 4 * kh;
      int col = 32 * t + r31;
      dotL[i * LDD + col] = accP[t][q];
    }
  __syncthreads();

  if (w == 0) {
    int k = l;
    int cnt = cnts_t[k * NCF + m];
    float n = bn2L[k];
    float cnk = cn2[k];
    for (int j = 0; j < CF; ++j) {
      float dS = dotL[j * LDD + k];
      float dC = dotL[j * LDD + 64 + k];
      float pvj = pvL[j];
      int lab = labL[j];
      bool seen = cnt > 0;
      float val = seen ? dS : dC;
      float nn  = seen ? n : cnk;
      out[((size_t)(m * 128 + j)) * K + k] = val * rsqrtf(fmaxf(nn * pvj, 1e-30f));
      if (k == lab) { n = seen ? (n + 2.f * dS + pvj) : pvj; cnt++; }
    }
  }
}

// =====================================================================
// FALLBACK PATH — round-1 pipeline, verbatim (known-correct)
// =====================================================================
__global__ __launch_bounds__(256) void ph1_chunk_sums(
    const float* __restrict__ inputs, const int* __restrict__ labels,
    float* __restrict__ sums, int* __restrict__ cnts, int NC, int C)
{
  __shared__ float acc[4 * K * 64];
  __shared__ int   hist[4 * K];
  const int bi    = blockIdx.x;
  const int chunk = bi / 12, slice = bi % 12;
  const int w = threadIdx.x >> 6, l = threadIdx.x & 63;

  for (int e = threadIdx.x; e < 4 * K * 64; e += 256) acc[e] = 0.f;
  hist[threadIdx.x] = 0;
  __syncthreads();

  const int C4 = C >> 2;
  const long long rbase = (long long)chunk * C + (long long)w * C4;
  float* accw = acc + w * (K * 64);
  for (int j = 0; j < C4; ++j) {
    long long r = rbase + j;
    int lab = labels[r];
    float v = inputs[r * D + slice * 64 + l];
    accw[lab * 64 + l] += v;
    if (slice == 0 && l == 0) hist[w * K + lab]++;
  }
  __syncthreads();

  float* sp = sums + (long long)chunk * (K * D) + slice * 64;
  for (int e = threadIdx.x; e < K * 64; e += 256) {
    int k = e >> 6, dl = e & 63;
    float s = acc[0*K*64 + e] + acc[1*K*64 + e] + acc[2*K*64 + e] + acc[3*K*64 + e];
    sp[k * D + dl] = s;
  }
  if (slice == 0 && threadIdx.x < K) {
    cnts[chunk * K + threadIdx.x] =
        hist[0*K + threadIdx.x] + hist[1*K + threadIdx.x] +
        hist[2*K + threadIdx.x] + hist[3*K + threadIdx.x];
  }
}

__global__ __launch_bounds__(256) void ph2a_scan_sums(float* __restrict__ sums, int NC)
{
  const int tid = blockIdx.x * 256 + threadIdx.x;
  float run = 0.f;
  for (int m = 0; m < NC; ++m) {
    long long idx = (long long)m * (K * D) + tid;
    float t = sums[idx];
    sums[idx] = run;
    run += t;
  }
}

__global__ void ph2b_scan_cnts(int* __restrict__ cnts, int NC)
{
  const int k = threadIdx.x;
  int run = 0;
  for (int m = 0; m < NC; ++m) {
    int t = cnts[m * K + k];
    cnts[m * K + k] = run;
    run += t;
  }
}

__global__ __launch_bounds__(256, 4) void ph3_scan(
    const float* __restrict__ inputs, const int* __restrict__ labels,
    const float* __restrict__ cavg, const float* __restrict__ base,
    const int* __restrict__ cnts, float* __restrict__ out, int NC, int C)
{
  const int bi = blockIdx.x;
  int chunk, quad;
  if (NC >= 8) {
    int xcd = bi & 7, slot = bi >> 3;
    chunk = xcd * (NC >> 3) + (slot >> 2);
    quad  = slot & 3;
  } else {
    chunk = bi >> 2; quad = bi & 3;
  }
  const int w = threadIdx.x >> 6, l = threadIdx.x & 63;
  const int k0 = (quad * 4 + w) * 4;

  const int cb = chunk * K + k0;
  bool vg0 = (cnts[cb+0] == 0), vg1 = (cnts[cb+1] == 0);
  bool vg2 = (cnts[cb+2] == 0), vg3 = (cnts[cb+3] == 0);

  const float4* bp = (const float4*)base + (long long)chunk * (K * D4);
  const float4* cp = (const float4*)cavg;

  float4 A0[3], A1[3], A2[3], A3[3];
#pragma unroll
  for (int t = 0; t < 3; ++t) {
    int o = t * 64 + l;
    A0[t] = vg0 ? cp[(k0+0)*D4 + o] : bp[(k0+0)*D4 + o];
    A1[t] = vg1 ? cp[(k0+1)*D4 + o] : bp[(k0+1)*D4 + o];
    A2[t] = vg2 ? cp[(k0+2)*D4 + o] : bp[(k0+2)*D4 + o];
    A3[t] = vg3 ? cp[(k0+3)*D4 + o] : bp[(k0+3)*D4 + o];
  }
  float n0 = 0.f, n1 = 0.f, n2 = 0.f, n3 = 0.f;
#pragma unroll
  for (int t = 0; t < 3; ++t) {
    n0 += d4f(A0[t], A0[t]); n1 += d4f(A1[t], A1[t]);
    n2 += d4f(A2[t], A2[t]); n3 += d4f(A3[t], A3[t]);
  }
#pragma unroll
  for (int m = 1; m <= 32; m <<= 1) {
    n0 += __shfl_xor(n0, m); n1 += __shfl_xor(n1, m);
    n2 += __shfl_xor(n2, m); n3 += __shfl_xor(n3, m);
  }

  const long long ibase = (long long)chunk * C;
  for (int j = 0; j < C; ++j) {
    const long long i = ibase + j;
    const int lab = labels[i];
    const float4* vp = (const float4*)inputs + i * D4;
    float4 v0 = vp[l], v1 = vp[64 + l], v2 = vp[128 + l];

    float p0 = d4f(A0[0], v0) + d4f(A0[1], v1) + d4f(A0[2], v2);
    float p1 = d4f(A1[0], v0) + d4f(A1[1], v1) + d4f(A1[2], v2);
    float p2 = d4f(A2[0], v0) + d4f(A2[1], v1) + d4f(A2[2], v2);
    float p3 = d4f(A3[0], v0) + d4f(A3[1], v1) + d4f(A3[2], v2);
    float pv = d4f(v0, v0) + d4f(v1, v1) + d4f(v2, v2);
#pragma unroll
    for (int m = 1; m <= 32; m <<= 1) {
      p0 += __shfl_xor(p0, m); p1 += __shfl_xor(p1, m);
      p2 += __shfl_xor(p2, m); p3 += __shfl_xor(p3, m);
      pv += __shfl_xor(pv, m);
    }
    if (l < 4) {
      float ps = (l == 0) ? p0 : (l == 1) ? p1 : (l == 2) ? p2 : p3;
      float ns = (l == 0) ? n0 : (l == 1) ? n1 : (l == 2) ? n2 : n3;
      out[i * K + k0 + l] = ps * rsqrtf(fmaxf(ns * pv, 1e-30f));
    }
#define UPD(idx) do { \
      if (vg##idx) { A##idx[0]=v0; A##idx[1]=v1; A##idx[2]=v2; n##idx = pv; vg##idx = false; } \
      else { A##idx[0]=a4(A##idx[0],v0); A##idx[1]=a4(A##idx[1],v1); A##idx[2]=a4(A##idx[2],v2); \
             n##idx += 2.f * p##idx + pv; } } while (0)
    if      (lab == k0 + 0) UPD(0);
    else if (lab == k0 + 1) UPD(1);
    else if (lab == k0 + 2) UPD(2);
    else if (lab == k0 + 3) UPD(3);
#undef UPD
  }
}

// =====================================================================
extern "C" void kernel_launch(void* const* d_in, const int* in_sizes, int n_in,
                              void* d_out, int out_size, void* d_ws, size_t ws_size,
                              hipStream_t stream)
{
  const float* inputs = (const float*)d_in[0];
  const int*   labels = (const int*)d_in[1];
  const float* cavg   = (const float*)d_in[2];
  float* out = (float*)d_out;
  const int N = in_sizes[1];

  const size_t szVb    = (size_t)32768 * D * 2;
  const size_t szSums  = (size_t)NCF * K * D * 4;
  const size_t szAux   = (size_t)16 * K * D * 4;
  const size_t szPv    = (size_t)32768 * 4;
  const size_t szCnt   = (size_t)K * NCF * 4;
  const size_t szCavgb = (size_t)K * D * 2;
  const size_t szCn2   = (size_t)K * 4;
  size_t need = szVb + szSums + szAux + szPv + szCnt + szCavgb + szCn2 + 8 * 256;

  if (N == 32768 && in_sizes[2] == K * D && ws_size >= need) {
    char* p = (char*)d_ws;
    auto take = [&](size_t b) { char* r = p; p += (b + 255) & ~(size_t)255; return r; };
    unsigned short* Vb    = (unsigned short*)take(szVb);
    float*          sums  = (float*)take(szSums);
    float*          aux   = (float*)take(szAux);
    float*          pv    = (float*)take(szPv);
    int*            cnts  = (int*)take(szCnt);
    unsigned short* cavgb = (unsigned short*)take(szCavgb);
    float*          cn2   = (float*)take(szCn2);

    hipLaunchKernelGGL(k1c, dim3(16), dim3(256), 0, stream, cavg, cavgb, cn2);
    hipLaunchKernelGGL(k2_fused, dim3(NCF), dim3(256), 0, stream,
                       inputs, labels, Vb, pv, sums, cnts);
    hipLaunchKernelGGL(k2b_scan_cnts, dim3(1), dim3(K), 0, stream, cnts, NCF);
    hipLaunchKernelGGL(k3a_scan_lo, dim3(16 * 192), dim3(256), 0, stream, sums, aux);
    hipLaunchKernelGGL(k3b_scan_hi, dim3(192), dim3(256), 0, stream, aux);
    hipLaunchKernelGGL(k4_mega, dim3(NCF), dim3(256), 0, stream,
                       Vb, sums, aux, cavgb, labels, pv, cnts, cn2, out);
    return;
  }

  // ---------------- fallback: round-1 pipeline ----------------
  int NC = 256;
  while (NC > 1) {
    size_t nd = (size_t)NC * K * D * 4 + (size_t)NC * K * 4;
    if (nd <= ws_size && (N % (NC * 4)) == 0) break;
    NC >>= 1;
  }
  const int C = N / NC;
  float* d_sums = (float*)d_ws;
  int*   d_cnts = (int*)((char*)d_ws + (size_t)NC * K * D * 4);

  hipLaunchKernelGGL(ph1_chunk_sums, dim3(NC * 12), dim3(256), 0, stream,
                     inputs, labels, d_sums, d_cnts, NC, C);
  hipLaunchKernelGGL(ph2a_scan_sums, dim3((K * D) / 256), dim3(256), 0, stream,
                     d_sums, NC);
  hipLaunchKernelGGL(ph2b_scan_cnts, dim3(1), dim3(64), 0, stream,
                     d_cnts, NC);
  hipLaunchKernelGGL(ph3_scan, dim3(NC * 4), dim3(256), 0, stream,
                     inputs, labels, cavg, d_sums, d_cnts, out, NC, C);
}